// Round 12
// baseline (119.545 us; speedup 1.0000x reference)
//
#include <hip/hip_runtime.h>
#include <hip/hip_bf16.h>

#define BT      8192
#define DIN     2048
#define DOUT    2048
#define NEXP    8
#define RANK    8
#define KX      2112         /* DIN + NEXP*RANK */
#define SCALING 1.0f         /* ALPHA / RANK = 8/8 */
#define SLOT    32768

typedef __bf16 bf16x8 __attribute__((ext_vector_type(8)));
typedef __bf16 bf16x4 __attribute__((ext_vector_type(4)));
typedef float  f32x4  __attribute__((ext_vector_type(4)));

/* ---- ws layout (bytes) ---- */
#define XB_OFF     0
#define XB_BYTES   (BT * KX * 2)
#define WB_OFF     (XB_OFF + XB_BYTES)
#define WB_BYTES   (DOUT * KX * 2)
#define ACAT_OFF   (WB_OFF + WB_BYTES)
#define ACAT_BYTES (128 * DIN * 2)

__device__ __forceinline__ void gload_lds16(const void* g, void* l) {
    __builtin_amdgcn_global_load_lds(
        (__attribute__((address_space(1))) void*)(g),
        (__attribute__((address_space(3))) void*)(l),
        16, 0, 0);
}

#define MFMA16(a, b, c) __builtin_amdgcn_mfma_f32_16x16x32_bf16((a), (b), (c), 0, 0, 0)

/* ---------------- prep: weights -> bf16 staged layouts ---------------- */
__global__ __launch_bounds__(256) void mole_prep(
    const float* __restrict__ Wf, const float* __restrict__ Bm,
    const float* __restrict__ Wr, const float* __restrict__ A,
    __bf16* __restrict__ WB, __bf16* __restrict__ ACAT)
{
    const int i = blockIdx.x * 256 + threadIdx.x;
    const int R1 = DOUT * (DIN / 4);
    const int R2 = DOUT * 64;
    if (i < R1) {
        const int o = i >> 9, c4 = i & 511;
        float4 v = ((const float4*)Wf)[(size_t)o * 512 + c4];
        bf16x4 b; b[0] = (__bf16)v.x; b[1] = (__bf16)v.y; b[2] = (__bf16)v.z; b[3] = (__bf16)v.w;
        *(bf16x4*)&WB[(size_t)o * KX + (c4 << 2)] = b;
    } else if (i < R1 + R2) {
        const int j = i - R1;
        const int o = j >> 6, c = j & 63;
        const int e = c >> 3, r = c & 7;
        WB[(size_t)o * KX + DIN + c] = (__bf16)Bm[((size_t)e * DOUT + o) * RANK + r];
    } else {
        const int j = i - (R1 + R2);
        const int r = j >> 9, c4 = j & 511;
        float4 v;
        if (r < 8)        v = ((const float4*)Wr)[(size_t)r * 512 + c4];
        else if (r < 72)  v = ((const float4*)A)[(size_t)(r - 8) * 512 + c4];
        else              v = make_float4(0.f, 0.f, 0.f, 0.f);
        bf16x4 b; b[0] = (__bf16)v.x; b[1] = (__bf16)v.y; b[2] = (__bf16)v.z; b[3] = (__bf16)v.w;
        *(bf16x4*)&ACAT[(size_t)r * DIN + (c4 << 2)] = b;
    }
}

/* ===== fused: x->bf16 (+XB write) + h/logit GEMM (full K in-register) +
   softmax + g-write. Block = 16 tokens, grid 512. ACAT (512 KB) L2-hot.
   HP buffer and softmax kernel eliminated. ===== */
__global__ __launch_bounds__(256) void mole_hfuse(
    const float* __restrict__ x, const __bf16* __restrict__ ACAT,
    const float* __restrict__ br,
    __bf16* __restrict__ XB, float* __restrict__ wOut)
{
    __shared__ __align__(16) __bf16 Bs[128][32];
    __shared__ __align__(16) __bf16 Xs[16][32];
    __shared__ float hbuf[16][80];
    __shared__ float wl[16][8];

    const int tid = threadIdx.x;
    const int wv  = tid >> 6, ln = tid & 63;
    const size_t t0 = (size_t)blockIdx.x * 16;

    /* ACAT staging: 2 gload_lds/thread (wave-uniform dest + lane*16B) */
    const int srow = (wv << 4) + (ln >> 2);
    const int scol = (ln & 3) << 3;
    const __bf16* gB0 = ACAT + srow * (size_t)DIN + scol;
    const __bf16* gB1 = gB0 + (size_t)64 * DIN;
    __bf16* lB0 = &Bs[(wv << 4)][0];
    __bf16* lB1 = &Bs[64 + (wv << 4)][0];

    /* x: threads 0-127, one float4/iter: row tid>>3, f4-col tid&7 */
    const int xr = tid >> 3;
    const int xc = (tid & 7) << 2;
    const float* gx  = x  + (t0 + xr) * (size_t)DIN + xc;
    __bf16*      gxb = XB + (t0 + xr) * (size_t)KX  + xc;

    const int fr = ln & 15;
    const int fk = (ln >> 4) << 3;

    f32x4 acc0 = {}, acc1 = {};

    for (int ks = 0; ks < DIN / 32; ++ks) {
        const int kb = ks * 32;
        gload_lds16(gB0 + kb, lB0);
        gload_lds16(gB1 + kb, lB1);
        if (tid < 128) {
            float4 v = *(const float4*)(gx + kb);
            bf16x4 b; b[0] = (__bf16)v.x; b[1] = (__bf16)v.y;
            b[2] = (__bf16)v.z; b[3] = (__bf16)v.w;
            *(bf16x4*)&Xs[xr][xc] = b;
            *(bf16x4*)(gxb + kb) = b;
        }
        __syncthreads();

        bf16x8 fa = *(const bf16x8*)&Xs[fr][fk];
        bf16x8 fb0 = *(const bf16x8*)&Bs[(wv << 5) + fr][fk];
        bf16x8 fb1 = *(const bf16x8*)&Bs[(wv << 5) + 16 + fr][fk];
        acc0 = MFMA16(fa, fb0, acc0);
        acc1 = MFMA16(fa, fb1, acc1);
        __syncthreads();
    }

    /* acc -> hbuf (cols < 72 only; wave wv owns cols [32wv, 32wv+32)) */
    const int crow = (ln >> 4) << 2;
    const int ccol = ln & 15;
    {
        const int c0 = (wv << 5) + ccol;
        if (c0 < 72) {
            #pragma unroll
            for (int r = 0; r < 4; ++r) hbuf[crow + r][c0] = acc0[r];
        }
        const int c1 = (wv << 5) + 16 + ccol;
        if (c1 < 72) {
            #pragma unroll
            for (int r = 0; r < 4; ++r) hbuf[crow + r][c1] = acc1[r];
        }
    }
    __syncthreads();

    /* softmax: threads 0-127 = 16 tokens x 8 experts (8-lane groups) */
    if (tid < 128) {
        const int tok = tid >> 3, e = tid & 7;
        float lg = hbuf[tok][e] + br[e];
        float mx = lg;
        mx = fmaxf(mx, __shfl_xor(mx, 1));
        mx = fmaxf(mx, __shfl_xor(mx, 2));
        mx = fmaxf(mx, __shfl_xor(mx, 4));
        float ex = expf(lg - mx);
        float sm = ex;
        sm += __shfl_xor(sm, 1);
        sm += __shfl_xor(sm, 2);
        sm += __shfl_xor(sm, 4);
        const float w = ex / sm;
        wl[tok][e] = w;
        wOut[(t0 + tok) * NEXP + e] = w;
    }
    __syncthreads();

    /* g = SCALING * w[e] * h -> XB tail cols (16 tok x 16 col-quads) */
    {
        const int tok = tid >> 4;
        const int c0  = (tid & 15) << 2;
        bf16x4 g4;
        #pragma unroll
        for (int j = 0; j < 4; ++j) {
            const int c = c0 + j;
            g4[j] = (__bf16)(SCALING * wl[tok][c >> 3] * hbuf[tok][8 + c]);
        }
        *(bf16x4*)&XB[(t0 + tok) * KX + DIN + c0] = g4;
    }
}

/* == main 256x256 GEMM: ring-4 BK=32, counted vmcnt (best measured, R10) ==
   C[8192,2048] = XB[8192,KX] * WB[2048,KX]^T + bias. 8 waves (2M x 4N),
   per-wave 128x64. LDS = 4 ring slots x 32 KB; swizzle phys16B =
   k ^ ((row>>1)&3) (0 conflicts, verified). Never vmcnt(0) until tail. */
__global__ __launch_bounds__(512, 1) void mole_gemm256(
    const __bf16* __restrict__ XBp, const __bf16* __restrict__ WBp,
    float* __restrict__ C, const float* __restrict__ bias)
{
    __shared__ __align__(16) char smem[131072];

    const int tid = threadIdx.x;
    const int wv  = tid >> 6, l = tid & 63;
    const int wm  = wv >> 2, wn = wv & 3;
    const int bid = blockIdx.x;
    const int xcd = bid & 7, ib = bid >> 3;
    const int tm = xcd * 4 + (ib & 3), tn = ib >> 2;
    const size_t m0 = (size_t)tm * 256, n0 = (size_t)tn * 256;

    const int op = wv >> 2, ww = wv & 3;
    const __bf16* gstage = (op == 0 ? XBp + (m0 + ww * 64) * KX
                                    : WBp + (n0 + ww * 64) * KX)
                         + (size_t)(l >> 2) * KX + (((l & 3) ^ ((l >> 3) & 3)) << 3);
    const int stageBase = op * 16384 + ww * 4096;

    const int fr = l & 15, fq = l >> 4;
    const int swz = (fq ^ ((fr >> 1) & 3)) << 4;
    const int aByte = (wm * 128 + fr) * 64 + swz;
    const int bByte = 16384 + (wn * 64 + fr) * 64 + swz;

    f32x4 acc[8][4] = {};
    bf16x8 fa0[8], fb0[4], fa1[8], fb1[4];

#define STAGE(S)                                                              \
    {                                                                         \
        char* dst = smem + ((S) & 3) * SLOT + stageBase;                      \
        const __bf16* g = gstage + (size_t)(S) * 32;                          \
        _Pragma("unroll")                                                     \
        for (int j = 0; j < 4; ++j)                                           \
            gload_lds16(g + (size_t)j * 16 * KX, dst + j * 1024);             \
    }

#define READS(S, FA, FB)                                                      \
    {                                                                         \
        const char* slot = smem + ((S) & 3) * SLOT;                           \
        _Pragma("unroll")                                                     \
        for (int nf = 0; nf < 4; ++nf)                                        \
            FB[nf] = *(const bf16x8*)(slot + bByte + nf * 1024);              \
        _Pragma("unroll")                                                     \
        for (int mf = 0; mf < 8; ++mf)                                        \
            FA[mf] = *(const bf16x8*)(slot + aByte + mf * 1024);              \
    }

#define STEP(S, VMN, DOSTAGE, DOREAD, FAc, FBc, FAn, FBn)                     \
    {                                                                         \
        asm volatile("s_waitcnt vmcnt(" #VMN ")" ::: "memory");               \
        __builtin_amdgcn_s_barrier();                                         \
        if (DOREAD) READS((S) + 1, FAn, FBn);                                 \
        if (DOSTAGE) STAGE((S) + 3);                                          \
        __builtin_amdgcn_sched_barrier(0);                                    \
        __builtin_amdgcn_s_setprio(1);                                        \
        _Pragma("unroll")                                                     \
        for (int mf = 0; mf < 8; ++mf)                                        \
            _Pragma("unroll")                                                 \
            for (int nf = 0; nf < 4; ++nf)                                    \
                acc[mf][nf] = MFMA16(FAc[mf], FBc[nf], acc[mf][nf]);          \
        __builtin_amdgcn_s_setprio(0);                                        \
    }

    STAGE(0); STAGE(1); STAGE(2);
    asm volatile("s_waitcnt vmcnt(8)" ::: "memory");
    __builtin_amdgcn_s_barrier();
    READS(0, fa0, fb0);

    #pragma unroll 1
    for (int s = 0; s < 62; s += 2) {
        STEP(s,     4, true, true, fa0, fb0, fa1, fb1);
        STEP(s + 1, 4, true, true, fa1, fb1, fa0, fb0);
    }
    STEP(62, 4, true,  true,  fa0, fb0, fa1, fb1);
    STEP(63, 4, false, true,  fa1, fb1, fa0, fb0);
    STEP(64, 0, false, true,  fa0, fb0, fa1, fb1);
    STEP(65, 0, false, false, fa1, fb1, fa0, fb0);
#undef STEP
#undef READS
#undef STAGE

    const size_t crow = m0 + wm * 128 + fq * 4;
    const size_t ccol = n0 + wn * 64 + fr;
    #pragma unroll
    for (int nf = 0; nf < 4; ++nf) {
        const float bv = bias[ccol + nf * 16];
        #pragma unroll
        for (int mf = 0; mf < 8; ++mf) {
            float* cp = C + (crow + (size_t)mf * 16) * DOUT + ccol + nf * 16;
            #pragma unroll
            for (int i = 0; i < 4; ++i)
                cp[(size_t)i * DOUT] = acc[mf][nf][i] + bv;
        }
    }
}

extern "C" void kernel_launch(void* const* d_in, const int* in_sizes, int n_in,
                              void* d_out, int out_size, void* d_ws, size_t ws_size,
                              hipStream_t stream) {
    const float* x  = (const float*)d_in[0];
    const float* Wf = (const float*)d_in[1];
    const float* bf = (const float*)d_in[2];
    const float* Wr = (const float*)d_in[3];
    const float* br = (const float*)d_in[4];
    const float* A  = (const float*)d_in[5];
    const float* Bm = (const float*)d_in[6];

    float* out0 = (float*)d_out;
    float* wOut = out0 + (size_t)BT * DOUT;

    char* ws = (char*)d_ws;
    __bf16* XB   = (__bf16*)(ws + XB_OFF);
    __bf16* WB   = (__bf16*)(ws + WB_OFF);
    __bf16* ACAT = (__bf16*)(ws + ACAT_OFF);

    /* 1. weights -> bf16 layouts */
    mole_prep<<<4864, 256, 0, stream>>>(Wf, Bm, Wr, A, WB, ACAT);
    /* 2. fused: x->bf16 + XB write + h/logit GEMM + softmax + g */
    mole_hfuse<<<BT / 16, 256, 0, stream>>>(x, ACAT, br, XB, wOut);
    /* 3. out = [xb|g] @ [Wfb|Bcat]^T + bf */
    mole_gemm256<<<256, 512, 0, stream>>>(XB, WB, out0, bf);
}

// Round 13
// 103.479 us; speedup vs baseline: 1.1553x; 1.1553x over previous
//
#include <hip/hip_runtime.h>
#include <hip/hip_bf16.h>

#define BT      8192
#define DIN     2048
#define DOUT    2048
#define NEXP    8
#define RANK    8
#define KX      2112         /* DIN + NEXP*RANK */
#define NSPLIT  4            /* K-split for the h-GEMM */
#define HLD     72           /* HP leading dim: cols 0-7 logits, 8-71 h */
#define SCALING 1.0f         /* ALPHA / RANK = 8/8 */
#define SLOT    32768

typedef __bf16 bf16x8 __attribute__((ext_vector_type(8)));
typedef __bf16 bf16x4 __attribute__((ext_vector_type(4)));
typedef float  f32x4  __attribute__((ext_vector_type(4)));

/* ---- ws layout (bytes) ---- */
#define XB_OFF     0
#define XB_BYTES   (BT * KX * 2)
#define WB_OFF     (XB_OFF + XB_BYTES)
#define WB_BYTES   (DOUT * KX * 2)
#define ACAT_OFF   (WB_OFF + WB_BYTES)
#define ACAT_BYTES (128 * DIN * 2)
#define HP_OFF     (ACAT_OFF + ACAT_BYTES)
#define HP_BYTES   (NSPLIT * BT * HLD * 4)

__device__ __forceinline__ void gload_lds16(const void* g, void* l) {
    __builtin_amdgcn_global_load_lds(
        (__attribute__((address_space(1))) void*)(g),
        (__attribute__((address_space(3))) void*)(l),
        16, 0, 0);
}

#define MFMA16(a, b, c) __builtin_amdgcn_mfma_f32_16x16x32_bf16((a), (b), (c), 0, 0, 0)

/* ---------------- prep: weights -> bf16 staged layouts ---------------- */
__global__ __launch_bounds__(256) void mole_prep(
    const float* __restrict__ Wf, const float* __restrict__ Bm,
    const float* __restrict__ Wr, const float* __restrict__ A,
    __bf16* __restrict__ WB, __bf16* __restrict__ ACAT)
{
    const int i = blockIdx.x * 256 + threadIdx.x;
    const int R1 = DOUT * (DIN / 4);
    const int R2 = DOUT * 64;
    if (i < R1) {
        const int o = i >> 9, c4 = i & 511;
        float4 v = ((const float4*)Wf)[(size_t)o * 512 + c4];
        bf16x4 b; b[0] = (__bf16)v.x; b[1] = (__bf16)v.y; b[2] = (__bf16)v.z; b[3] = (__bf16)v.w;
        *(bf16x4*)&WB[(size_t)o * KX + (c4 << 2)] = b;
    } else if (i < R1 + R2) {
        const int j = i - R1;
        const int o = j >> 6, c = j & 63;
        const int e = c >> 3, r = c & 7;
        WB[(size_t)o * KX + DIN + c] = (__bf16)Bm[((size_t)e * DOUT + o) * RANK + r];
    } else {
        const int j = i - (R1 + R2);
        const int r = j >> 9, c4 = j & 511;
        float4 v;
        if (r < 8)        v = ((const float4*)Wr)[(size_t)r * 512 + c4];
        else if (r < 72)  v = ((const float4*)A)[(size_t)(r - 8) * 512 + c4];
        else              v = make_float4(0.f, 0.f, 0.f, 0.f);
        bf16x4 b; b[0] = (__bf16)v.x; b[1] = (__bf16)v.y; b[2] = (__bf16)v.z; b[3] = (__bf16)v.w;
        *(bf16x4*)&ACAT[(size_t)r * DIN + (c4 << 2)] = b;
    }
}

/* ==== fused h-GEMM: x(fp32)->bf16 convert + XB side-write + MFMA vs ACAT.
   Grid (64,1,4): block (m,z) = 128 tokens x K-chunk 512. HP[z][t][0..71] =
   [logit partials (Wr rows) | h partials (A rows)]. x read ONCE. ==== */
__global__ __launch_bounds__(256) void mole_hconv(
    const float* __restrict__ x, const __bf16* __restrict__ ACAT,
    __bf16* __restrict__ XB, float* __restrict__ HP)
{
    __shared__ __align__(16) __bf16 Xs[128][32];
    __shared__ __align__(16) __bf16 Bs[128][32];

    const int tid = threadIdx.x;
    const int wv  = tid >> 6, ln = tid & 63;
    const int wr  = wv >> 1, wc = wv & 1;
    const size_t m0 = (size_t)blockIdx.x * 128;
    const int kStart = blockIdx.z * (DIN / NSPLIT);
    float* C = HP + (size_t)blockIdx.z * BT * HLD;

    const int xr = tid >> 3;
    const int xc = (tid & 7) << 2;
    const float* gx  = x  + (m0 + xr) * (size_t)DIN + kStart + xc;
    __bf16*      gxb = XB + (m0 + xr) * (size_t)KX  + kStart + xc;

    const int srow = (wv << 4) + (ln >> 2);
    const int scol = (ln & 3) << 3;
    const __bf16* gB0 = ACAT + srow * (size_t)DIN + kStart + scol;
    const __bf16* gB1 = gB0 + (size_t)64 * DIN;
    __bf16* lB0 = &Bs[(wv << 4)][0];
    __bf16* lB1 = &Bs[64 + (wv << 4)][0];

    f32x4 acc[4][4] = {};
    const int fr = ln & 15;
    const int fk = (ln >> 4) << 3;

    for (int ks = 0; ks < (DIN / NSPLIT) / 32; ++ks) {
        gload_lds16(gB0, lB0);
        gload_lds16(gB1, lB1);
        gB0 += 32; gB1 += 32;
        #pragma unroll
        for (int j = 0; j < 4; ++j) {
            float4 v = *(const float4*)(gx + (size_t)(32 * j) * DIN + 32 * ks);
            bf16x4 b; b[0] = (__bf16)v.x; b[1] = (__bf16)v.y;
            b[2] = (__bf16)v.z; b[3] = (__bf16)v.w;
            *(bf16x4*)&Xs[xr + 32 * j][xc] = b;
            *(bf16x4*)(gxb + (size_t)(32 * j) * KX + 32 * ks) = b;
        }
        __syncthreads();

        bf16x8 af[4], bfr[4];
        #pragma unroll
        for (int m = 0; m < 4; ++m)
            af[m] = *(const bf16x8*)&Xs[(wr << 6) + (m << 4) + fr][fk];
        #pragma unroll
        for (int n = 0; n < 4; ++n)
            bfr[n] = *(const bf16x8*)&Bs[(wc << 6) + (n << 4) + fr][fk];
        #pragma unroll
        for (int m = 0; m < 4; ++m)
            #pragma unroll
            for (int n = 0; n < 4; ++n)
                acc[m][n] = MFMA16(af[m], bfr[n], acc[m][n]);
        __syncthreads();
    }

    const int cr = (ln >> 4) << 2;
    const int cc = ln & 15;
    #pragma unroll
    for (int n = 0; n < 4; ++n) {
        const int col = (wc << 6) + (n << 4) + cc;
        if (col < HLD) {
            #pragma unroll
            for (int m = 0; m < 4; ++m) {
                const size_t row = m0 + (wr << 6) + (m << 4) + cr;
                #pragma unroll
                for (int r = 0; r < 4; ++r)
                    C[(row + r) * (size_t)HLD + col] = acc[m][n][r];
            }
        }
    }
}

/* --------- per-token: logits (HP cols 0-7 + br) -> softmax -> w; g -> XB --- */
__global__ __launch_bounds__(256) void mole_softmax_g(
    const float* __restrict__ HP, const float* __restrict__ br,
    float* __restrict__ wOut, __bf16* __restrict__ XB)
{
    const int t   = blockIdx.x * 4 + (threadIdx.x >> 6);
    const int tid = threadIdx.x & 63;
    float h = 0.0f;
    #pragma unroll
    for (int sp = 0; sp < NSPLIT; ++sp)
        h += HP[((size_t)sp * BT + t) * HLD + 8 + tid];

    float lg[NEXP];
    #pragma unroll
    for (int e = 0; e < NEXP; ++e) {
        lg[e] = br[e];
        #pragma unroll
        for (int sp = 0; sp < NSPLIT; ++sp)
            lg[e] += HP[((size_t)sp * BT + t) * HLD + e];
    }
    float mx = lg[0];
    #pragma unroll
    for (int e = 1; e < NEXP; ++e) mx = fmaxf(mx, lg[e]);
    float ex[NEXP], den = 0.0f;
    #pragma unroll
    for (int e = 0; e < NEXP; ++e) { ex[e] = expf(lg[e] - mx); den += ex[e]; }

    const float w_my = ex[tid >> 3] / den;
    XB[(size_t)t * KX + DIN + tid] = (__bf16)(SCALING * w_my * h);
    if (tid < NEXP) wOut[(size_t)t * NEXP + tid] = ex[tid] / den;
}

/* == main 256x256 GEMM: ring-4 BK=32, counted vmcnt (best measured, R10) ==
   C[8192,2048] = XB[8192,KX] * WB[2048,KX]^T + bias. 8 waves (2M x 4N),
   per-wave 128x64. LDS = 4 ring slots x 32 KB; swizzle phys16B =
   k ^ ((row>>1)&3) (0 conflicts, verified). Never vmcnt(0) until tail. */
__global__ __launch_bounds__(512, 1) void mole_gemm256(
    const __bf16* __restrict__ XBp, const __bf16* __restrict__ WBp,
    float* __restrict__ C, const float* __restrict__ bias)
{
    __shared__ __align__(16) char smem[131072];

    const int tid = threadIdx.x;
    const int wv  = tid >> 6, l = tid & 63;
    const int wm  = wv >> 2, wn = wv & 3;
    const int bid = blockIdx.x;
    const int xcd = bid & 7, ib = bid >> 3;
    const int tm = xcd * 4 + (ib & 3), tn = ib >> 2;
    const size_t m0 = (size_t)tm * 256, n0 = (size_t)tn * 256;

    const int op = wv >> 2, ww = wv & 3;
    const __bf16* gstage = (op == 0 ? XBp + (m0 + ww * 64) * KX
                                    : WBp + (n0 + ww * 64) * KX)
                         + (size_t)(l >> 2) * KX + (((l & 3) ^ ((l >> 3) & 3)) << 3);
    const int stageBase = op * 16384 + ww * 4096;

    const int fr = l & 15, fq = l >> 4;
    const int swz = (fq ^ ((fr >> 1) & 3)) << 4;
    const int aByte = (wm * 128 + fr) * 64 + swz;
    const int bByte = 16384 + (wn * 64 + fr) * 64 + swz;

    f32x4 acc[8][4] = {};
    bf16x8 fa0[8], fb0[4], fa1[8], fb1[4];

#define STAGE(S)                                                              \
    {                                                                         \
        char* dst = smem + ((S) & 3) * SLOT + stageBase;                      \
        const __bf16* g = gstage + (size_t)(S) * 32;                          \
        _Pragma("unroll")                                                     \
        for (int j = 0; j < 4; ++j)                                           \
            gload_lds16(g + (size_t)j * 16 * KX, dst + j * 1024);             \
    }

#define READS(S, FA, FB)                                                      \
    {                                                                         \
        const char* slot = smem + ((S) & 3) * SLOT;                           \
        _Pragma("unroll")                                                     \
        for (int nf = 0; nf < 4; ++nf)                                        \
            FB[nf] = *(const bf16x8*)(slot + bByte + nf * 1024);              \
        _Pragma("unroll")                                                     \
        for (int mf = 0; mf < 8; ++mf)                                        \
            FA[mf] = *(const bf16x8*)(slot + aByte + mf * 1024);              \
    }

#define STEP(S, VMN, DOSTAGE, DOREAD, FAc, FBc, FAn, FBn)                     \
    {                                                                         \
        asm volatile("s_waitcnt vmcnt(" #VMN ")" ::: "memory");               \
        __builtin_amdgcn_s_barrier();                                         \
        if (DOREAD) READS((S) + 1, FAn, FBn);                                 \
        if (DOSTAGE) STAGE((S) + 3);                                          \
        __builtin_amdgcn_sched_barrier(0);                                    \
        __builtin_amdgcn_s_setprio(1);                                        \
        _Pragma("unroll")                                                     \
        for (int mf = 0; mf < 8; ++mf)                                        \
            _Pragma("unroll")                                                 \
            for (int nf = 0; nf < 4; ++nf)                                    \
                acc[mf][nf] = MFMA16(FAc[mf], FBc[nf], acc[mf][nf]);          \
        __builtin_amdgcn_s_setprio(0);                                        \
    }

    STAGE(0); STAGE(1); STAGE(2);
    asm volatile("s_waitcnt vmcnt(8)" ::: "memory");
    __builtin_amdgcn_s_barrier();
    READS(0, fa0, fb0);

    #pragma unroll 1
    for (int s = 0; s < 62; s += 2) {
        STEP(s,     4, true, true, fa0, fb0, fa1, fb1);
        STEP(s + 1, 4, true, true, fa1, fb1, fa0, fb0);
    }
    STEP(62, 4, true,  true,  fa0, fb0, fa1, fb1);
    STEP(63, 4, false, true,  fa1, fb1, fa0, fb0);
    STEP(64, 0, false, true,  fa0, fb0, fa1, fb1);
    STEP(65, 0, false, false, fa1, fb1, fa0, fb0);
#undef STEP
#undef READS
#undef STAGE

    const size_t crow = m0 + wm * 128 + fq * 4;
    const size_t ccol = n0 + wn * 64 + fr;
    #pragma unroll
    for (int nf = 0; nf < 4; ++nf) {
        const float bv = bias[ccol + nf * 16];
        #pragma unroll
        for (int mf = 0; mf < 8; ++mf) {
            float* cp = C + (crow + (size_t)mf * 16) * DOUT + ccol + nf * 16;
            #pragma unroll
            for (int i = 0; i < 4; ++i)
                cp[(size_t)i * DOUT] = acc[mf][nf][i] + bv;
        }
    }
}

extern "C" void kernel_launch(void* const* d_in, const int* in_sizes, int n_in,
                              void* d_out, int out_size, void* d_ws, size_t ws_size,
                              hipStream_t stream) {
    const float* x  = (const float*)d_in[0];
    const float* Wf = (const float*)d_in[1];
    const float* bf = (const float*)d_in[2];
    const float* Wr = (const float*)d_in[3];
    const float* br = (const float*)d_in[4];
    const float* A  = (const float*)d_in[5];
    const float* Bm = (const float*)d_in[6];

    float* out0 = (float*)d_out;
    float* wOut = out0 + (size_t)BT * DOUT;

    char* ws = (char*)d_ws;
    __bf16* XB   = (__bf16*)(ws + XB_OFF);
    __bf16* WB   = (__bf16*)(ws + WB_OFF);
    __bf16* ACAT = (__bf16*)(ws + ACAT_OFF);
    float*  HP   = (float*)(ws + HP_OFF);

    /* 1. weights -> bf16 layouts */
    mole_prep<<<4864, 256, 0, stream>>>(Wf, Bm, Wr, A, WB, ACAT);
    /* 2. fused: x->bf16 (+XB side-write) + [logit|h] partials vs ACAT */
    mole_hconv<<<dim3(64, 1, NSPLIT), 256, 0, stream>>>(x, ACAT, XB, HP);
    /* 3. softmax(+br) -> w out; g -> XB tail cols */
    mole_softmax_g<<<BT / 4, 256, 0, stream>>>(HP, br, wOut, XB);
    /* 4. out = [xb|g] @ [Wfb|Bcat]^T + bf */
    mole_gemm256<<<256, 512, 0, stream>>>(XB, WB, out0, bf);
}